// Round 1
// baseline (839.921 us; speedup 1.0000x reference)
//
#include <hip/hip_runtime.h>
#include <math.h>

// EncoderBlock: B=4 S=2048 D=1024 H=16 DK=64 DFF=4096
// Pipeline: transpose weights->bf16 | ln1 | QKV gemms | flash attn | wo gemm(+x)
//           | ln2 | ffn1 gemm(relu) | ffn2 gemm(+y1)
// All GEMMs: bf16 MFMA 16x16x32, fp32 accum. Workspace budget: 136 MB.

typedef unsigned short u16;
typedef __bf16 bf16x8 __attribute__((ext_vector_type(8)));
typedef float f32x4 __attribute__((ext_vector_type(4)));

__device__ __forceinline__ u16 f2bf(float f) {
  unsigned u = __float_as_uint(f);
  u += 0x7fffu + ((u >> 16) & 1u);   // RNE
  return (u16)(u >> 16);
}

// ---------- transpose fp32 [K,N] -> bf16 [N,K] ----------
__global__ __launch_bounds__(256) void k_transpose_bf16(
    const float* __restrict__ src, u16* __restrict__ dst, int K, int N) {
  __shared__ float tile[32][33];
  int n0 = blockIdx.x * 32, k0 = blockIdx.y * 32;
  int c = threadIdx.x & 31, r0 = threadIdx.x >> 5;  // 8 rows per pass
#pragma unroll
  for (int i = 0; i < 32; i += 8)
    tile[r0 + i][c] = src[(size_t)(k0 + r0 + i) * N + n0 + c];
  __syncthreads();
#pragma unroll
  for (int i = 0; i < 32; i += 8)
    dst[(size_t)(n0 + r0 + i) * K + k0 + c] = f2bf(tile[c][r0 + i]);
}

// ---------- layernorm (ddof=1, /(std+eps)) -> bf16 ----------
__global__ __launch_bounds__(256) void k_layernorm_bf16(
    const float* __restrict__ x, const float* __restrict__ w,
    const float* __restrict__ b, u16* __restrict__ out) {
  const int D = 1024;
  int row = blockIdx.x, tid = threadIdx.x;
  const float4* xr = (const float4*)(x + (size_t)row * D);
  float4 v = xr[tid];
  float s = v.x + v.y + v.z + v.w;
  float ss = v.x * v.x + v.y * v.y + v.z * v.z + v.w * v.w;
#pragma unroll
  for (int off = 1; off < 64; off <<= 1) {
    s += __shfl_xor(s, off);
    ss += __shfl_xor(ss, off);
  }
  __shared__ float rs[4], rss[4];
  int wave = tid >> 6, lane = tid & 63;
  if (lane == 0) { rs[wave] = s; rss[wave] = ss; }
  __syncthreads();
  float S_ = rs[0] + rs[1] + rs[2] + rs[3];
  float SS = rss[0] + rss[1] + rss[2] + rss[3];
  float mean = S_ * (1.0f / D);
  float var = (SS - (float)D * mean * mean) * (1.0f / (D - 1));
  float inv = 1.0f / (sqrtf(fmaxf(var, 0.0f)) + 1e-6f);
  float4 wv = ((const float4*)w)[tid], bv = ((const float4*)b)[tid];
  u16* orow = out + (size_t)row * D + tid * 4;
  orow[0] = f2bf(wv.x * (v.x - mean) * inv + bv.x);
  orow[1] = f2bf(wv.y * (v.y - mean) * inv + bv.y);
  orow[2] = f2bf(wv.z * (v.z - mean) * inv + bv.z);
  orow[3] = f2bf(wv.w * (v.w - mean) * inv + bv.w);
}

// ---------- GEMM: C[M,N] = A[M,K]bf16 @ Bt[N,K]bf16^T + bias (+res)(relu) ----------
// 128x128 tile, 4 waves, each wave 64x64 via 4x4 MFMAs of 16x16x32.
template <bool RELU, bool HAS_RES, bool OUT_BF16>
__global__ __launch_bounds__(256) void k_gemm(
    const u16* __restrict__ A, const u16* __restrict__ Bt,
    const float* __restrict__ bias, const float* __restrict__ res,
    void* __restrict__ outp, int M, int N, int K) {
  __shared__ __align__(16) u16 As[128 * 32];
  __shared__ __align__(16) u16 Bs[128 * 32];
  const int tid = threadIdx.x;
  const int lane = tid & 63, wave = tid >> 6;
  const int quad = lane >> 4, l16 = lane & 15;
  const int m0 = blockIdx.y * 128, n0 = blockIdx.x * 128;
  const int wm = (wave >> 1) * 64, wn = (wave & 1) * 64;

  f32x4 zero = {0.0f, 0.0f, 0.0f, 0.0f};
  f32x4 acc[4][4];
#pragma unroll
  for (int i = 0; i < 4; i++)
#pragma unroll
    for (int j = 0; j < 4; j++) acc[i][j] = zero;

  for (int k0 = 0; k0 < K; k0 += 32) {
    __syncthreads();
    {  // stage A,B tiles: 128 rows x 32 cols each = 512 16B chunks
      int c = tid, r = c >> 2, o = c & 3;
      ((uint4*)As)[c] = *(const uint4*)(A + (size_t)(m0 + r) * K + k0 + o * 8);
      ((uint4*)Bs)[c] = *(const uint4*)(Bt + (size_t)(n0 + r) * K + k0 + o * 8);
      c = tid + 256; r = c >> 2; o = c & 3;
      ((uint4*)As)[c] = *(const uint4*)(A + (size_t)(m0 + r) * K + k0 + o * 8);
      ((uint4*)Bs)[c] = *(const uint4*)(Bt + (size_t)(n0 + r) * K + k0 + o * 8);
    }
    __syncthreads();
    bf16x8 af[4], bfr[4];
#pragma unroll
    for (int mb = 0; mb < 4; mb++)
      af[mb] = *(const bf16x8*)&As[(wm + mb * 16 + l16) * 32 + quad * 8];
#pragma unroll
    for (int nb = 0; nb < 4; nb++)
      bfr[nb] = *(const bf16x8*)&Bs[(wn + nb * 16 + l16) * 32 + quad * 8];
#pragma unroll
    for (int mb = 0; mb < 4; mb++)
#pragma unroll
      for (int nb = 0; nb < 4; nb++)
        acc[mb][nb] = __builtin_amdgcn_mfma_f32_16x16x32_bf16(
            af[mb], bfr[nb], acc[mb][nb], 0, 0, 0);
  }
  // epilogue: C/D layout col=lane&15, row=quad*4+reg (m89-verified)
#pragma unroll
  for (int mb = 0; mb < 4; mb++) {
#pragma unroll
    for (int nb = 0; nb < 4; nb++) {
      int col = n0 + wn + nb * 16 + l16;
      float bb = bias[col];
#pragma unroll
      for (int r = 0; r < 4; r++) {
        int row = m0 + wm + mb * 16 + quad * 4 + r;
        float vv = acc[mb][nb][r] + bb;
        if (HAS_RES) vv += res[(size_t)row * N + col];
        if (RELU) vv = fmaxf(vv, 0.0f);
        if (OUT_BF16) ((u16*)outp)[(size_t)row * N + col] = f2bf(vv);
        else ((float*)outp)[(size_t)row * N + col] = vv;
      }
    }
  }
}

// ---------- flash attention: block = (b,h,qtile of 64), 4 waves x 16 q-rows ----------
__global__ __launch_bounds__(256) void k_attention(
    const u16* __restrict__ q, const u16* __restrict__ k,
    const u16* __restrict__ v, const int* __restrict__ mask,
    u16* __restrict__ out) {
  const int S = 2048, D = 1024;
  int blk = blockIdx.x;
  int qt = blk & 31, h = (blk >> 5) & 15, b = blk >> 9;
  int tid = threadIdx.x, lane = tid & 63, wave = tid >> 6;
  int quad = lane >> 4, l16 = lane & 15;

  __shared__ __align__(16) u16 Qs[64 * 64];
  __shared__ __align__(16) u16 Ks[64 * 64];
  __shared__ __align__(16) u16 Vs[64 * 64];  // transposed [dk][key]
  __shared__ __align__(16) u16 Ps[4][16 * 64];

  const u16* qbp = q + ((size_t)(b * S + qt * 64) * D + h * 64);
  {  // stage Q tile 64x64
    int c = tid, r = c >> 3, o = c & 7;
    ((uint4*)Qs)[c] = *(const uint4*)(qbp + (size_t)r * D + o * 8);
    c = tid + 256; r = c >> 3; o = c & 7;
    ((uint4*)Qs)[c] = *(const uint4*)(qbp + (size_t)r * D + o * 8);
  }
  __syncthreads();
  bf16x8 aq0 = *(const bf16x8*)&Qs[(wave * 16 + l16) * 64 + quad * 8];
  bf16x8 aq1 = *(const bf16x8*)&Qs[(wave * 16 + l16) * 64 + 32 + quad * 8];

  f32x4 zero = {0.0f, 0.0f, 0.0f, 0.0f};
  f32x4 acc[4];
#pragma unroll
  for (int ob = 0; ob < 4; ob++) acc[ob] = zero;
  float m_run[4], l_run[4];
#pragma unroll
  for (int r = 0; r < 4; r++) { m_run[r] = -__builtin_inff(); l_run[r] = 0.0f; }
  const float scl = 0.125f;  // 1/sqrt(64)

  for (int kt = 0; kt < 32; kt++) {
    __syncthreads();  // protect LDS reuse from previous iteration's readers
    const u16* kbp = k + ((size_t)(b * S + kt * 64) * D + h * 64);
    const u16* vbp = v + ((size_t)(b * S + kt * 64) * D + h * 64);
    {  // stage K tile [key][d]
      int c = tid, r = c >> 3, o = c & 7;
      ((uint4*)Ks)[c] = *(const uint4*)(kbp + (size_t)r * D + o * 8);
      c = tid + 256; r = c >> 3; o = c & 7;
      ((uint4*)Ks)[c] = *(const uint4*)(kbp + (size_t)r * D + o * 8);
    }
    {  // stage V transposed [dk][key]
      int key = tid >> 2, dk0 = (tid & 3) * 16;
      union { uint4 u[2]; u16 s[16]; } tmp;
      tmp.u[0] = *(const uint4*)(vbp + (size_t)key * D + dk0);
      tmp.u[1] = *(const uint4*)(vbp + (size_t)key * D + dk0 + 8);
#pragma unroll
      for (int j = 0; j < 16; j++) Vs[(dk0 + j) * 64 + key] = tmp.s[j];
    }
    __syncthreads();
    // S16x64 = Q @ K^T
    f32x4 sa[4];
#pragma unroll
    for (int kb = 0; kb < 4; kb++) {
      bf16x8 b0 = *(const bf16x8*)&Ks[(kb * 16 + l16) * 64 + quad * 8];
      bf16x8 b1 = *(const bf16x8*)&Ks[(kb * 16 + l16) * 64 + 32 + quad * 8];
      f32x4 z = zero;
      z = __builtin_amdgcn_mfma_f32_16x16x32_bf16(aq0, b0, z, 0, 0, 0);
      z = __builtin_amdgcn_mfma_f32_16x16x32_bf16(aq1, b1, z, 0, 0, 0);
      sa[kb] = z;
    }
    // scale + mask
#pragma unroll
    for (int kb = 0; kb < 4; kb++) {
      int mv = mask[b * S + kt * 64 + kb * 16 + l16];
#pragma unroll
      for (int r = 0; r < 4; r++) {
        float sc = sa[kb][r] * scl;
        sa[kb][r] = mv ? sc : -__builtin_inff();
      }
    }
    // online softmax (rows = quad*4+r; row-reduce over 16 lanes sharing quad)
#pragma unroll
    for (int r = 0; r < 4; r++) {
      float tm = fmaxf(fmaxf(sa[0][r], sa[1][r]), fmaxf(sa[2][r], sa[3][r]));
#pragma unroll
      for (int off = 1; off < 16; off <<= 1) tm = fmaxf(tm, __shfl_xor(tm, off));
      float mn = fmaxf(m_run[r], tm);
      float al = __expf(m_run[r] - mn);  // exp(-inf)=0 on first iter
      float rsum = 0.0f;
#pragma unroll
      for (int kb = 0; kb < 4; kb++) {
        float p = __expf(sa[kb][r] - mn);
        sa[kb][r] = p;
        rsum += p;
      }
#pragma unroll
      for (int off = 1; off < 16; off <<= 1) rsum += __shfl_xor(rsum, off);
      l_run[r] = l_run[r] * al + rsum;
      m_run[r] = mn;
#pragma unroll
      for (int ob = 0; ob < 4; ob++) acc[ob][r] *= al;
    }
    // P: C-layout -> LDS -> A-layout (m120 pattern)
#pragma unroll
    for (int kb = 0; kb < 4; kb++)
#pragma unroll
      for (int r = 0; r < 4; r++)
        Ps[wave][(quad * 4 + r) * 64 + kb * 16 + l16] = f2bf(sa[kb][r]);
    __syncthreads();
    bf16x8 ap0 = *(const bf16x8*)&Ps[wave][l16 * 64 + quad * 8];
    bf16x8 ap1 = *(const bf16x8*)&Ps[wave][l16 * 64 + 32 + quad * 8];
#pragma unroll
    for (int ob = 0; ob < 4; ob++) {
      bf16x8 bv0 = *(const bf16x8*)&Vs[(ob * 16 + l16) * 64 + quad * 8];
      bf16x8 bv1 = *(const bf16x8*)&Vs[(ob * 16 + l16) * 64 + 32 + quad * 8];
      acc[ob] = __builtin_amdgcn_mfma_f32_16x16x32_bf16(ap0, bv0, acc[ob], 0, 0, 0);
      acc[ob] = __builtin_amdgcn_mfma_f32_16x16x32_bf16(ap1, bv1, acc[ob], 0, 0, 0);
    }
  }
#pragma unroll
  for (int r = 0; r < 4; r++) {
    float inv = 1.0f / l_run[r];
    size_t rowoff =
        (size_t)(b * S + qt * 64 + wave * 16 + quad * 4 + r) * D + h * 64;
#pragma unroll
    for (int ob = 0; ob < 4; ob++)
      out[rowoff + ob * 16 + l16] = f2bf(acc[ob][r] * inv);
  }
}

extern "C" void kernel_launch(void* const* d_in, const int* in_sizes, int n_in,
                              void* d_out, int out_size, void* d_ws,
                              size_t ws_size, hipStream_t stream) {
  const float* x    = (const float*)d_in[0];
  const int*   mask = (const int*)d_in[1];
  const float* wq = (const float*)d_in[2];   const float* bq = (const float*)d_in[3];
  const float* wk = (const float*)d_in[4];   const float* bk = (const float*)d_in[5];
  const float* wv = (const float*)d_in[6];   const float* bv = (const float*)d_in[7];
  const float* wo = (const float*)d_in[8];   const float* bo = (const float*)d_in[9];
  const float* w1 = (const float*)d_in[10];  const float* b1 = (const float*)d_in[11];
  const float* w2 = (const float*)d_in[12];  const float* b2 = (const float*)d_in[13];
  const float* ln1w = (const float*)d_in[14]; const float* ln1b = (const float*)d_in[15];
  const float* ln2w = (const float*)d_in[16]; const float* ln2b = (const float*)d_in[17];
  float* outp = (float*)d_out;

  // workspace layout (MB): weights 0..24, xn/y1n 24, q 40, k 56, v 72, attn 88,
  // y1 104..136. hb aliases 40..104 (q/k/v/attn dead by ffn1). Total 136 MB.
  char* ws = (char*)d_ws;
  const size_t MB = 1024 * 1024;
  u16* wqT = (u16*)(ws + 0 * MB);
  u16* wkT = (u16*)(ws + 2 * MB);
  u16* wvT = (u16*)(ws + 4 * MB);
  u16* woT = (u16*)(ws + 6 * MB);
  u16* w1T = (u16*)(ws + 8 * MB);
  u16* w2T = (u16*)(ws + 16 * MB);
  u16* xn  = (u16*)(ws + 24 * MB);  // reused as y1n after ln2
  u16* qb  = (u16*)(ws + 40 * MB);
  u16* kb  = (u16*)(ws + 56 * MB);
  u16* vb  = (u16*)(ws + 72 * MB);
  u16* attn = (u16*)(ws + 88 * MB);
  float* y1 = (float*)(ws + 104 * MB);
  u16* hb  = (u16*)(ws + 40 * MB);  // alias

  k_transpose_bf16<<<dim3(32, 32), 256, 0, stream>>>(wq, wqT, 1024, 1024);
  k_transpose_bf16<<<dim3(32, 32), 256, 0, stream>>>(wk, wkT, 1024, 1024);
  k_transpose_bf16<<<dim3(32, 32), 256, 0, stream>>>(wv, wvT, 1024, 1024);
  k_transpose_bf16<<<dim3(32, 32), 256, 0, stream>>>(wo, woT, 1024, 1024);
  k_transpose_bf16<<<dim3(128, 32), 256, 0, stream>>>(w1, w1T, 1024, 4096);
  k_transpose_bf16<<<dim3(32, 128), 256, 0, stream>>>(w2, w2T, 4096, 1024);

  k_layernorm_bf16<<<8192, 256, 0, stream>>>(x, ln1w, ln1b, xn);

  dim3 g1(1024 / 128, 8192 / 128);
  k_gemm<false, false, true><<<g1, 256, 0, stream>>>(xn, wqT, bq, nullptr, qb, 8192, 1024, 1024);
  k_gemm<false, false, true><<<g1, 256, 0, stream>>>(xn, wkT, bk, nullptr, kb, 8192, 1024, 1024);
  k_gemm<false, false, true><<<g1, 256, 0, stream>>>(xn, wvT, bv, nullptr, vb, 8192, 1024, 1024);

  k_attention<<<2048, 256, 0, stream>>>(qb, kb, vb, mask, attn);

  k_gemm<false, true, false><<<g1, 256, 0, stream>>>(attn, woT, bo, x, y1, 8192, 1024, 1024);

  k_layernorm_bf16<<<8192, 256, 0, stream>>>(y1, ln2w, ln2b, xn);

  dim3 g2(4096 / 128, 8192 / 128);
  k_gemm<true, false, true><<<g2, 256, 0, stream>>>(xn, w1T, b1, nullptr, hb, 8192, 4096, 1024);

  k_gemm<false, true, false><<<g1, 256, 0, stream>>>(hb, w2T, b2, y1, outp, 8192, 1024, 4096);
}

// Round 2
// 754.571 us; speedup vs baseline: 1.1131x; 1.1131x over previous
//
#include <hip/hip_runtime.h>
#include <math.h>

// EncoderBlock: B=4 S=2048 D=1024 H=16 DK=64 DFF=4096
// R2: m97-style global_load_lds staging in GEMMs; attention LDS conflicts
//     eliminated via chunk-XOR (Q/K), rotation+XOR (V^T), XOR (P) swizzles.

typedef unsigned short u16;
typedef __bf16 bf16x8 __attribute__((ext_vector_type(8)));
typedef float f32x4 __attribute__((ext_vector_type(4)));

typedef __attribute__((address_space(1))) const void* as1_cvp;
typedef __attribute__((address_space(3))) void* as3_vp;

__device__ __forceinline__ void async_copy16(const void* g, void* l) {
  __builtin_amdgcn_global_load_lds((as1_cvp)g, (as3_vp)l, 16, 0, 0);
}

__device__ __forceinline__ u16 f2bf(float f) {
  unsigned u = __float_as_uint(f);
  u += 0x7fffu + ((u >> 16) & 1u);  // RNE
  return (u16)(u >> 16);
}

// ---------- transpose fp32 [K,N] -> bf16 [N,K] ----------
__global__ __launch_bounds__(256) void k_transpose_bf16(
    const float* __restrict__ src, u16* __restrict__ dst, int K, int N) {
  __shared__ float tile[32][33];
  int n0 = blockIdx.x * 32, k0 = blockIdx.y * 32;
  int c = threadIdx.x & 31, r0 = threadIdx.x >> 5;
#pragma unroll
  for (int i = 0; i < 32; i += 8)
    tile[r0 + i][c] = src[(size_t)(k0 + r0 + i) * N + n0 + c];
  __syncthreads();
#pragma unroll
  for (int i = 0; i < 32; i += 8)
    dst[(size_t)(n0 + r0 + i) * K + k0 + c] = f2bf(tile[c][r0 + i]);
}

// ---------- layernorm (ddof=1, /(std+eps)) -> bf16 ----------
__global__ __launch_bounds__(256) void k_layernorm_bf16(
    const float* __restrict__ x, const float* __restrict__ w,
    const float* __restrict__ b, u16* __restrict__ out) {
  const int D = 1024;
  int row = blockIdx.x, tid = threadIdx.x;
  const float4* xr = (const float4*)(x + (size_t)row * D);
  float4 v = xr[tid];
  float s = v.x + v.y + v.z + v.w;
  float ss = v.x * v.x + v.y * v.y + v.z * v.z + v.w * v.w;
#pragma unroll
  for (int off = 1; off < 64; off <<= 1) {
    s += __shfl_xor(s, off);
    ss += __shfl_xor(ss, off);
  }
  __shared__ float rs[4], rss[4];
  int wave = tid >> 6, lane = tid & 63;
  if (lane == 0) { rs[wave] = s; rss[wave] = ss; }
  __syncthreads();
  float S_ = rs[0] + rs[1] + rs[2] + rs[3];
  float SS = rss[0] + rss[1] + rss[2] + rss[3];
  float mean = S_ * (1.0f / D);
  float var = (SS - (float)D * mean * mean) * (1.0f / (D - 1));
  float inv = 1.0f / (sqrtf(fmaxf(var, 0.0f)) + 1e-6f);
  float4 wv = ((const float4*)w)[tid], bv = ((const float4*)b)[tid];
  u16* orow = out + (size_t)row * D + tid * 4;
  orow[0] = f2bf(wv.x * (v.x - mean) * inv + bv.x);
  orow[1] = f2bf(wv.y * (v.y - mean) * inv + bv.y);
  orow[2] = f2bf(wv.z * (v.z - mean) * inv + bv.z);
  orow[3] = f2bf(wv.w * (v.w - mean) * inv + bv.w);
}

// ---------- GEMM: C[M,N] = A[M,K]bf16 @ Bt[N,K]^T + bias (+res)(relu) ----------
// 128x128 tile, BK=32, 4 waves, m97-style global_load_lds staging.
template <bool RELU, bool HAS_RES, bool OUT_BF16>
__global__ __launch_bounds__(256) void k_gemm(
    const u16* __restrict__ A, const u16* __restrict__ Bt,
    const float* __restrict__ bias, const float* __restrict__ res,
    void* __restrict__ outp, int M, int N, int K) {
  __shared__ __align__(16) u16 As[128 * 32];
  __shared__ __align__(16) u16 Bs[128 * 32];
  const int tid = threadIdx.x;
  const int lane = tid & 63, wave = tid >> 6;
  const int quad = lane >> 4, l16 = lane & 15;
  const int m0 = blockIdx.y * 128, n0 = blockIdx.x * 128;
  const int wm = (wave >> 1) * 64, wn = (wave & 1) * 64;

  // DMA source rows/cols: chunk c -> row=c>>2, col=(c&3)*8
  const int r0 = tid >> 2, o0 = (tid & 3) * 8;  // c1 = tid+256 -> row r0+64
  const u16* a0 = A + (size_t)(m0 + r0) * K + o0;
  const u16* a1 = A + (size_t)(m0 + r0 + 64) * K + o0;
  const u16* b0p = Bt + (size_t)(n0 + r0) * K + o0;
  const u16* b1p = Bt + (size_t)(n0 + r0 + 64) * K + o0;
  u16* lA0 = As + tid * 8;  u16* lA1 = As + (tid + 256) * 8;
  u16* lB0 = Bs + tid * 8;  u16* lB1 = Bs + (tid + 256) * 8;

  f32x4 zero = {0.0f, 0.0f, 0.0f, 0.0f};
  f32x4 acc[4][4];
#pragma unroll
  for (int i = 0; i < 4; i++)
#pragma unroll
    for (int j = 0; j < 4; j++) acc[i][j] = zero;

  for (int k0 = 0; k0 < K; k0 += 32) {
    __syncthreads();
    async_copy16(a0 + k0, lA0);
    async_copy16(a1 + k0, lA1);
    async_copy16(b0p + k0, lB0);
    async_copy16(b1p + k0, lB1);
    __syncthreads();
    bf16x8 af[4], bfr[4];
#pragma unroll
    for (int mb = 0; mb < 4; mb++)
      af[mb] = *(const bf16x8*)&As[(wm + mb * 16 + l16) * 32 + quad * 8];
#pragma unroll
    for (int nb = 0; nb < 4; nb++)
      bfr[nb] = *(const bf16x8*)&Bs[(wn + nb * 16 + l16) * 32 + quad * 8];
#pragma unroll
    for (int mb = 0; mb < 4; mb++)
#pragma unroll
      for (int nb = 0; nb < 4; nb++)
        acc[mb][nb] = __builtin_amdgcn_mfma_f32_16x16x32_bf16(
            af[mb], bfr[nb], acc[mb][nb], 0, 0, 0);
  }
  // epilogue: C/D layout col=lane&15, row=quad*4+reg
#pragma unroll
  for (int mb = 0; mb < 4; mb++) {
#pragma unroll
    for (int nb = 0; nb < 4; nb++) {
      int col = n0 + wn + nb * 16 + l16;
      float bb = bias[col];
#pragma unroll
      for (int r = 0; r < 4; r++) {
        int row = m0 + wm + mb * 16 + quad * 4 + r;
        float vv = acc[mb][nb][r] + bb;
        if (HAS_RES) vv += res[(size_t)row * N + col];
        if (RELU) vv = fmaxf(vv, 0.0f);
        if (OUT_BF16) ((u16*)outp)[(size_t)row * N + col] = f2bf(vv);
        else ((float*)outp)[(size_t)row * N + col] = vv;
      }
    }
  }
}

// ---------- flash attention: block = (b,h,qtile of 64) ----------
// Q/K tiles: DMA-staged, chunk-XOR swizzle o' = o ^ (row&7).
// V^T tile: key' = ((key + 16*(dk>>4))&63) ^ (8*((dk>>2)&1))  (CF writes+reads)
// P tile:   col' = col ^ ((row>>2)<<4)                        (CF writes+reads)
__global__ __launch_bounds__(256) void k_attention(
    const u16* __restrict__ q, const u16* __restrict__ k,
    const u16* __restrict__ v, const int* __restrict__ mask,
    u16* __restrict__ out) {
  const int S = 2048, D = 1024;
  int blk = blockIdx.x;
  int qt = blk & 31, h = (blk >> 5) & 15, bb = blk >> 9;
  int tid = threadIdx.x, lane = tid & 63, wave = tid >> 6;
  int quad = lane >> 4, l16 = lane & 15;
  int sw = l16 & 7;

  __shared__ __align__(16) u16 Qs[64 * 64];
  __shared__ __align__(16) u16 Ks[64 * 64];
  __shared__ __align__(16) u16 Vs[64 * 64];
  __shared__ __align__(16) u16 Ps[4][16 * 64];

  // DMA source for swizzled 64x64 tile: chunk c -> row=c>>3, o=(c&7)^(row&7)
  const int srow0 = tid >> 3, so0 = ((tid & 7) ^ (srow0 & 7)) * 8;
  const int srow1 = (tid + 256) >> 3, so1 = ((tid & 7) ^ (srow1 & 7)) * 8;

  const u16* qbp = q + ((size_t)(bb * S + qt * 64) * D + h * 64);
  async_copy16(qbp + (size_t)srow0 * D + so0, Qs + tid * 8);
  async_copy16(qbp + (size_t)srow1 * D + so1, Qs + (tid + 256) * 8);
  __syncthreads();
  int qrow = wave * 16 + l16;
  bf16x8 aq0 = *(const bf16x8*)&Qs[qrow * 64 + ((quad ^ sw) * 8)];
  bf16x8 aq1 = *(const bf16x8*)&Qs[qrow * 64 + (((quad ^ 4) ^ sw) * 8)];

  f32x4 zero = {0.0f, 0.0f, 0.0f, 0.0f};
  f32x4 acc[4];
#pragma unroll
  for (int ob = 0; ob < 4; ob++) acc[ob] = zero;
  float m_run[4], l_run[4];
#pragma unroll
  for (int r = 0; r < 4; r++) { m_run[r] = -__builtin_inff(); l_run[r] = 0.0f; }
  const float scl = 0.125f;  // 1/sqrt(64)

  // V staging constants: thread loads V[key][g*16..g*16+15]
  const int vkey = tid >> 2, vg = tid & 3;
  const int vkbase = (vkey + 16 * vg) & 63;

  for (int kt = 0; kt < 32; kt++) {
    __syncthreads();
    const u16* kbp = k + ((size_t)(bb * S + kt * 64) * D + h * 64);
    const u16* vbp = v + ((size_t)(bb * S + kt * 64) * D + h * 64);
    async_copy16(kbp + (size_t)srow0 * D + so0, Ks + tid * 8);
    async_copy16(kbp + (size_t)srow1 * D + so1, Ks + (tid + 256) * 8);
    {  // V^T staged with swizzle
      union { uint4 u[2]; u16 s[16]; } tmp;
      tmp.u[0] = *(const uint4*)(vbp + (size_t)vkey * D + vg * 16);
      tmp.u[1] = *(const uint4*)(vbp + (size_t)vkey * D + vg * 16 + 8);
#pragma unroll
      for (int j = 0; j < 16; j++) {
        int keyp = vkbase ^ (8 * ((j >> 2) & 1));
        Vs[(vg * 16 + j) * 64 + keyp] = tmp.s[j];
      }
    }
    __syncthreads();
    // S 16x64 = Q @ K^T
    f32x4 sa[4];
#pragma unroll
    for (int kb = 0; kb < 4; kb++) {
      int krow = kb * 16 + l16;
      bf16x8 kf0 = *(const bf16x8*)&Ks[krow * 64 + ((quad ^ sw) * 8)];
      bf16x8 kf1 = *(const bf16x8*)&Ks[krow * 64 + (((quad ^ 4) ^ sw) * 8)];
      f32x4 z = zero;
      z = __builtin_amdgcn_mfma_f32_16x16x32_bf16(aq0, kf0, z, 0, 0, 0);
      z = __builtin_amdgcn_mfma_f32_16x16x32_bf16(aq1, kf1, z, 0, 0, 0);
      sa[kb] = z;
    }
#pragma unroll
    for (int kb = 0; kb < 4; kb++) {
      int mv = mask[bb * S + kt * 64 + kb * 16 + l16];
#pragma unroll
      for (int r = 0; r < 4; r++) {
        float sc = sa[kb][r] * scl;
        sa[kb][r] = mv ? sc : -__builtin_inff();
      }
    }
    // online softmax: rows = quad*4+r, reduce across 16 lanes of quad
#pragma unroll
    for (int r = 0; r < 4; r++) {
      float tm = fmaxf(fmaxf(sa[0][r], sa[1][r]), fmaxf(sa[2][r], sa[3][r]));
#pragma unroll
      for (int off = 1; off < 16; off <<= 1) tm = fmaxf(tm, __shfl_xor(tm, off));
      float mn = fmaxf(m_run[r], tm);
      float al = __expf(m_run[r] - mn);
      float rsum = 0.0f;
#pragma unroll
      for (int kb = 0; kb < 4; kb++) {
        float p = __expf(sa[kb][r] - mn);
        sa[kb][r] = p;
        rsum += p;
      }
#pragma unroll
      for (int off = 1; off < 16; off <<= 1) rsum += __shfl_xor(rsum, off);
      l_run[r] = l_run[r] * al + rsum;
      m_run[r] = mn;
#pragma unroll
      for (int ob = 0; ob < 4; ob++) acc[ob][r] *= al;
    }
    // P: C-layout -> LDS (XOR swizzle, wave-private, no barrier needed)
#pragma unroll
    for (int kb = 0; kb < 4; kb++)
#pragma unroll
      for (int r = 0; r < 4; r++)
        Ps[wave][(quad * 4 + r) * 64 + ((kb * 16 + l16) ^ (quad << 4))] =
            f2bf(sa[kb][r]);
    int psw = (l16 >> 2) << 4;
    bf16x8 ap0 = *(const bf16x8*)&Ps[wave][l16 * 64 + ((quad * 8) ^ psw)];
    bf16x8 ap1 = *(const bf16x8*)&Ps[wave][l16 * 64 + ((32 + quad * 8) ^ psw)];
    int vsw = 8 * ((l16 >> 2) & 1);
#pragma unroll
    for (int ob = 0; ob < 4; ob++) {
      int vrow = ob * 16 + l16;
      int kb0 = ((quad * 8 + 16 * ob) & 63) ^ vsw;
      int kb1 = ((32 + quad * 8 + 16 * ob) & 63) ^ vsw;
      bf16x8 vf0 = *(const bf16x8*)&Vs[vrow * 64 + kb0];
      bf16x8 vf1 = *(const bf16x8*)&Vs[vrow * 64 + kb1];
      acc[ob] = __builtin_amdgcn_mfma_f32_16x16x32_bf16(ap0, vf0, acc[ob], 0, 0, 0);
      acc[ob] = __builtin_amdgcn_mfma_f32_16x16x32_bf16(ap1, vf1, acc[ob], 0, 0, 0);
    }
  }
#pragma unroll
  for (int r = 0; r < 4; r++) {
    float inv = 1.0f / l_run[r];
    size_t rowoff =
        (size_t)(bb * S + qt * 64 + wave * 16 + quad * 4 + r) * D + h * 64;
#pragma unroll
    for (int ob = 0; ob < 4; ob++)
      out[rowoff + ob * 16 + l16] = f2bf(acc[ob][r] * inv);
  }
}

extern "C" void kernel_launch(void* const* d_in, const int* in_sizes, int n_in,
                              void* d_out, int out_size, void* d_ws,
                              size_t ws_size, hipStream_t stream) {
  const float* x    = (const float*)d_in[0];
  const int*   mask = (const int*)d_in[1];
  const float* wq = (const float*)d_in[2];   const float* bq = (const float*)d_in[3];
  const float* wk = (const float*)d_in[4];   const float* bk = (const float*)d_in[5];
  const float* wv = (const float*)d_in[6];   const float* bv = (const float*)d_in[7];
  const float* wo = (const float*)d_in[8];   const float* bo = (const float*)d_in[9];
  const float* w1 = (const float*)d_in[10];  const float* b1 = (const float*)d_in[11];
  const float* w2 = (const float*)d_in[12];  const float* b2 = (const float*)d_in[13];
  const float* ln1w = (const float*)d_in[14]; const float* ln1b = (const float*)d_in[15];
  const float* ln2w = (const float*)d_in[16]; const float* ln2b = (const float*)d_in[17];
  float* outp = (float*)d_out;

  char* ws = (char*)d_ws;
  const size_t MB = 1024 * 1024;
  u16* wqT = (u16*)(ws + 0 * MB);
  u16* wkT = (u16*)(ws + 2 * MB);
  u16* wvT = (u16*)(ws + 4 * MB);
  u16* woT = (u16*)(ws + 6 * MB);
  u16* w1T = (u16*)(ws + 8 * MB);
  u16* w2T = (u16*)(ws + 16 * MB);
  u16* xn  = (u16*)(ws + 24 * MB);  // reused as y1n after ln2
  u16* qb  = (u16*)(ws + 40 * MB);
  u16* kb  = (u16*)(ws + 56 * MB);
  u16* vb  = (u16*)(ws + 72 * MB);
  u16* attn = (u16*)(ws + 88 * MB);
  float* y1 = (float*)(ws + 104 * MB);
  u16* hb  = (u16*)(ws + 40 * MB);  // alias over q/k/v (dead by ffn1)

  k_transpose_bf16<<<dim3(32, 32), 256, 0, stream>>>(wq, wqT, 1024, 1024);
  k_transpose_bf16<<<dim3(32, 32), 256, 0, stream>>>(wk, wkT, 1024, 1024);
  k_transpose_bf16<<<dim3(32, 32), 256, 0, stream>>>(wv, wvT, 1024, 1024);
  k_transpose_bf16<<<dim3(32, 32), 256, 0, stream>>>(wo, woT, 1024, 1024);
  k_transpose_bf16<<<dim3(128, 32), 256, 0, stream>>>(w1, w1T, 1024, 4096);
  k_transpose_bf16<<<dim3(32, 128), 256, 0, stream>>>(w2, w2T, 4096, 1024);

  k_layernorm_bf16<<<8192, 256, 0, stream>>>(x, ln1w, ln1b, xn);

  dim3 g1(1024 / 128, 8192 / 128);
  k_gemm<false, false, true><<<g1, 256, 0, stream>>>(xn, wqT, bq, nullptr, qb, 8192, 1024, 1024);
  k_gemm<false, false, true><<<g1, 256, 0, stream>>>(xn, wkT, bk, nullptr, kb, 8192, 1024, 1024);
  k_gemm<false, false, true><<<g1, 256, 0, stream>>>(xn, wvT, bv, nullptr, vb, 8192, 1024, 1024);

  k_attention<<<2048, 256, 0, stream>>>(qb, kb, vb, mask, attn);

  k_gemm<false, true, false><<<g1, 256, 0, stream>>>(attn, woT, bo, x, y1, 8192, 1024, 1024);

  k_layernorm_bf16<<<8192, 256, 0, stream>>>(y1, ln2w, ln2b, xn);

  dim3 g2(4096 / 128, 8192 / 128);
  k_gemm<true, false, true><<<g2, 256, 0, stream>>>(xn, w1T, b1, nullptr, hb, 8192, 4096, 1024);

  k_gemm<false, true, false><<<g1, 256, 0, stream>>>(hb, w2T, b2, y1, outp, 8192, 1024, 4096);
}

// Round 3
// 746.606 us; speedup vs baseline: 1.1250x; 1.0107x over previous
//
#include <hip/hip_runtime.h>
#include <math.h>

// EncoderBlock: B=4 S=2048 D=1024 H=16 DK=64 DFF=4096
// R3: attention 512-thr blocks (128 q-rows, Q in regs, Ps overlays Qs, LDS
//     32KB, halved V^T staging); fused QKV GEMM N=3072 with pre-scaled Q path.

typedef unsigned short u16;
typedef __bf16 bf16x8 __attribute__((ext_vector_type(8)));
typedef float f32x4 __attribute__((ext_vector_type(4)));

typedef __attribute__((address_space(1))) const void* as1_cvp;
typedef __attribute__((address_space(3))) void* as3_vp;

__device__ __forceinline__ void async_copy16(const void* g, void* l) {
  __builtin_amdgcn_global_load_lds((as1_cvp)g, (as3_vp)l, 16, 0, 0);
}

__device__ __forceinline__ u16 f2bf(float f) {
  unsigned u = __float_as_uint(f);
  u += 0x7fffu + ((u >> 16) & 1u);  // RNE
  return (u16)(u >> 16);
}

// ---------- transpose fp32 [K,N] -> bf16 [N,K], optional scale ----------
__global__ __launch_bounds__(256) void k_transpose_bf16(
    const float* __restrict__ src, u16* __restrict__ dst, int K, int N,
    float scale) {
  __shared__ float tile[32][33];
  int n0 = blockIdx.x * 32, k0 = blockIdx.y * 32;
  int c = threadIdx.x & 31, r0 = threadIdx.x >> 5;
#pragma unroll
  for (int i = 0; i < 32; i += 8)
    tile[r0 + i][c] = src[(size_t)(k0 + r0 + i) * N + n0 + c];
  __syncthreads();
#pragma unroll
  for (int i = 0; i < 32; i += 8)
    dst[(size_t)(n0 + r0 + i) * K + k0 + c] = f2bf(tile[c][r0 + i] * scale);
}

// ---------- pack QKV bias (bq scaled) ----------
__global__ __launch_bounds__(256) void k_pack_bias(
    const float* __restrict__ bq, const float* __restrict__ bk,
    const float* __restrict__ bv, float* __restrict__ out, float qscale) {
  int i = blockIdx.x * 256 + threadIdx.x;
  float v;
  if (i < 1024) v = bq[i] * qscale;
  else if (i < 2048) v = bk[i - 1024];
  else v = bv[i - 2048];
  out[i] = v;
}

// ---------- layernorm (ddof=1, /(std+eps)) -> bf16 ----------
__global__ __launch_bounds__(256) void k_layernorm_bf16(
    const float* __restrict__ x, const float* __restrict__ w,
    const float* __restrict__ b, u16* __restrict__ out) {
  const int D = 1024;
  int row = blockIdx.x, tid = threadIdx.x;
  const float4* xr = (const float4*)(x + (size_t)row * D);
  float4 v = xr[tid];
  float s = v.x + v.y + v.z + v.w;
  float ss = v.x * v.x + v.y * v.y + v.z * v.z + v.w * v.w;
#pragma unroll
  for (int off = 1; off < 64; off <<= 1) {
    s += __shfl_xor(s, off);
    ss += __shfl_xor(ss, off);
  }
  __shared__ float rs[4], rss[4];
  int wave = tid >> 6, lane = tid & 63;
  if (lane == 0) { rs[wave] = s; rss[wave] = ss; }
  __syncthreads();
  float S_ = rs[0] + rs[1] + rs[2] + rs[3];
  float SS = rss[0] + rss[1] + rss[2] + rss[3];
  float mean = S_ * (1.0f / D);
  float var = (SS - (float)D * mean * mean) * (1.0f / (D - 1));
  float inv = 1.0f / (sqrtf(fmaxf(var, 0.0f)) + 1e-6f);
  float4 wv = ((const float4*)w)[tid], bv = ((const float4*)b)[tid];
  u16* orow = out + (size_t)row * D + tid * 4;
  orow[0] = f2bf(wv.x * (v.x - mean) * inv + bv.x);
  orow[1] = f2bf(wv.y * (v.y - mean) * inv + bv.y);
  orow[2] = f2bf(wv.z * (v.z - mean) * inv + bv.z);
  orow[3] = f2bf(wv.w * (v.w - mean) * inv + bv.w);
}

// ---------- GEMM: C[M,N] = A[M,K]bf16 @ Bt[N,K]^T + bias (+res)(relu) ----------
template <bool RELU, bool HAS_RES, bool OUT_BF16>
__global__ __launch_bounds__(256) void k_gemm(
    const u16* __restrict__ A, const u16* __restrict__ Bt,
    const float* __restrict__ bias, const float* __restrict__ res,
    void* __restrict__ outp, int M, int N, int K) {
  __shared__ __align__(16) u16 As[128 * 32];
  __shared__ __align__(16) u16 Bs[128 * 32];
  const int tid = threadIdx.x;
  const int lane = tid & 63, wave = tid >> 6;
  const int quad = lane >> 4, l16 = lane & 15;
  const int m0 = blockIdx.y * 128, n0 = blockIdx.x * 128;
  const int wm = (wave >> 1) * 64, wn = (wave & 1) * 64;

  const int r0 = tid >> 2, o0 = (tid & 3) * 8;
  const u16* a0 = A + (size_t)(m0 + r0) * K + o0;
  const u16* a1 = A + (size_t)(m0 + r0 + 64) * K + o0;
  const u16* b0p = Bt + (size_t)(n0 + r0) * K + o0;
  const u16* b1p = Bt + (size_t)(n0 + r0 + 64) * K + o0;
  u16* lA0 = As + tid * 8;  u16* lA1 = As + (tid + 256) * 8;
  u16* lB0 = Bs + tid * 8;  u16* lB1 = Bs + (tid + 256) * 8;

  f32x4 zero = {0.0f, 0.0f, 0.0f, 0.0f};
  f32x4 acc[4][4];
#pragma unroll
  for (int i = 0; i < 4; i++)
#pragma unroll
    for (int j = 0; j < 4; j++) acc[i][j] = zero;

  for (int k0 = 0; k0 < K; k0 += 32) {
    __syncthreads();
    async_copy16(a0 + k0, lA0);
    async_copy16(a1 + k0, lA1);
    async_copy16(b0p + k0, lB0);
    async_copy16(b1p + k0, lB1);
    __syncthreads();
    bf16x8 af[4], bfr[4];
#pragma unroll
    for (int mb = 0; mb < 4; mb++)
      af[mb] = *(const bf16x8*)&As[(wm + mb * 16 + l16) * 32 + quad * 8];
#pragma unroll
    for (int nb = 0; nb < 4; nb++)
      bfr[nb] = *(const bf16x8*)&Bs[(wn + nb * 16 + l16) * 32 + quad * 8];
#pragma unroll
    for (int mb = 0; mb < 4; mb++)
#pragma unroll
      for (int nb = 0; nb < 4; nb++)
        acc[mb][nb] = __builtin_amdgcn_mfma_f32_16x16x32_bf16(
            af[mb], bfr[nb], acc[mb][nb], 0, 0, 0);
  }
#pragma unroll
  for (int mb = 0; mb < 4; mb++) {
#pragma unroll
    for (int nb = 0; nb < 4; nb++) {
      int col = n0 + wn + nb * 16 + l16;
      float bb = bias[col];
#pragma unroll
      for (int r = 0; r < 4; r++) {
        int row = m0 + wm + mb * 16 + quad * 4 + r;
        float vv = acc[mb][nb][r] + bb;
        if (HAS_RES) vv += res[(size_t)row * N + col];
        if (RELU) vv = fmaxf(vv, 0.0f);
        if (OUT_BF16) ((u16*)outp)[(size_t)row * N + col] = f2bf(vv);
        else ((float*)outp)[(size_t)row * N + col] = vv;
      }
    }
  }
}

// ---------- flash attention, 512 threads, 128 q-rows per block ----------
// qkv: fused [8192][3072] bf16 (q | k | v), q pre-scaled by 1/8.
// Q/K LDS: chunk-XOR swizzle o' = o ^ (row&7)  (on 8-elem chunks).
// V^T LDS: key' = key ^ (8*((dk>>3)&7)).
// P: per-wave region overlaid on Qs; col' = col ^ (quad<<4).
__global__ __launch_bounds__(512, 6) void k_attention(
    const u16* __restrict__ qkv, const int* __restrict__ mask,
    u16* __restrict__ out) {
  const int S = 2048, D = 1024, QS = 3072;
  int blk = blockIdx.x;
  int qt = blk & 15, h = (blk >> 4) & 15, bb = blk >> 8;
  int tid = threadIdx.x, lane = tid & 63, wave = tid >> 6;
  int quad = lane >> 4, l16 = lane & 15;
  int sw = l16 & 7;

  __shared__ __align__(16) u16 Qs[128 * 64];  // reused as Ps[wave][16*64]
  __shared__ __align__(16) u16 Ks[64 * 64];
  __shared__ __align__(16) u16 Vs[64 * 64];

  const int qrowbase = bb * S + qt * 128;
  // Q DMA: chunks c=tid, tid+512: row=c>>3, o=((c&7)^(row&7))*8
  {
    int c0 = tid, r0 = c0 >> 3, o0 = ((c0 & 7) ^ (r0 & 7)) * 8;
    int c1 = tid + 512, r1 = c1 >> 3, o1 = ((c1 & 7) ^ (r1 & 7)) * 8;
    async_copy16(qkv + (size_t)(qrowbase + r0) * QS + h * 64 + o0, Qs + c0 * 8);
    async_copy16(qkv + (size_t)(qrowbase + r1) * QS + h * 64 + o1, Qs + c1 * 8);
  }
  __syncthreads();
  int qrow = wave * 16 + l16;
  bf16x8 aq0 = *(const bf16x8*)&Qs[qrow * 64 + ((quad ^ sw) * 8)];
  bf16x8 aq1 = *(const bf16x8*)&Qs[qrow * 64 + (((quad ^ 4) ^ sw) * 8)];

  f32x4 zero = {0.0f, 0.0f, 0.0f, 0.0f};
  f32x4 acc[4];
#pragma unroll
  for (int ob = 0; ob < 4; ob++) acc[ob] = zero;
  float m_run[4], l_run[4];
#pragma unroll
  for (int r = 0; r < 4; r++) { m_run[r] = -__builtin_inff(); l_run[r] = 0.0f; }

  // K DMA pattern (one chunk per thread)
  const int krow = tid >> 3, ko = ((tid & 7) ^ (krow & 7)) * 8;
  // V staging: thread loads V[vkey][8*vf .. +7]
  const int vkey = tid >> 3, vf = tid & 7;
  u16* Ps = Qs + wave * 1024;

  for (int kt = 0; kt < 32; kt++) {
    __syncthreads();
    const int kb0 = bb * S + kt * 64;
    async_copy16(qkv + (size_t)(kb0 + krow) * QS + 1024 + h * 64 + ko,
                 Ks + tid * 8);
    {
      union { uint4 u; u16 s[8]; } tmp;
      tmp.u = *(const uint4*)(qkv + (size_t)(kb0 + vkey) * QS + 2048 + h * 64 +
                              vf * 8);
#pragma unroll
      for (int j = 0; j < 8; j++)
        Vs[(8 * vf + j) * 64 + (vkey ^ (8 * vf))] = tmp.s[j];
    }
    __syncthreads();
    // S 16x64 per wave = Q @ K^T
    f32x4 sa[4];
#pragma unroll
    for (int kb = 0; kb < 4; kb++) {
      int kr = kb * 16 + l16;
      bf16x8 kf0 = *(const bf16x8*)&Ks[kr * 64 + ((quad ^ sw) * 8)];
      bf16x8 kf1 = *(const bf16x8*)&Ks[kr * 64 + (((quad ^ 4) ^ sw) * 8)];
      f32x4 z = zero;
      z = __builtin_amdgcn_mfma_f32_16x16x32_bf16(aq0, kf0, z, 0, 0, 0);
      z = __builtin_amdgcn_mfma_f32_16x16x32_bf16(aq1, kf1, z, 0, 0, 0);
      sa[kb] = z;
    }
#pragma unroll
    for (int kb = 0; kb < 4; kb++) {
      int mv = mask[bb * S + kt * 64 + kb * 16 + l16];
#pragma unroll
      for (int r = 0; r < 4; r++)
        sa[kb][r] = mv ? sa[kb][r] : -__builtin_inff();
    }
    // online softmax: rows = quad*4+r, reduce across the 16 lanes of quad
#pragma unroll
    for (int r = 0; r < 4; r++) {
      float tm = fmaxf(fmaxf(sa[0][r], sa[1][r]), fmaxf(sa[2][r], sa[3][r]));
#pragma unroll
      for (int off = 1; off < 16; off <<= 1) tm = fmaxf(tm, __shfl_xor(tm, off));
      float mn = fmaxf(m_run[r], tm);
      float al = __expf(m_run[r] - mn);
      float rsum = 0.0f;
#pragma unroll
      for (int kb = 0; kb < 4; kb++) {
        float p = __expf(sa[kb][r] - mn);
        sa[kb][r] = p;
        rsum += p;
      }
#pragma unroll
      for (int off = 1; off < 16; off <<= 1) rsum += __shfl_xor(rsum, off);
      l_run[r] = l_run[r] * al + rsum;
      m_run[r] = mn;
#pragma unroll
      for (int ob = 0; ob < 4; ob++) acc[ob][r] *= al;
    }
    // P: C-layout -> LDS (wave-private region; in-wave DS ordering suffices)
#pragma unroll
    for (int kb = 0; kb < 4; kb++)
#pragma unroll
      for (int r = 0; r < 4; r++)
        Ps[(quad * 4 + r) * 64 + ((kb * 16 + l16) ^ (quad << 4))] =
            f2bf(sa[kb][r]);
    int psw = (l16 >> 2) << 4;
    bf16x8 ap0 = *(const bf16x8*)&Ps[l16 * 64 + ((quad * 8) ^ psw)];
    bf16x8 ap1 = *(const bf16x8*)&Ps[l16 * 64 + ((32 + quad * 8) ^ psw)];
#pragma unroll
    for (int ob = 0; ob < 4; ob++) {
      int vrow = ob * 16 + l16;
      int g8 = 8 * ((vrow >> 3) & 7);
      bf16x8 vf0 = *(const bf16x8*)&Vs[vrow * 64 + ((quad * 8) ^ g8)];
      bf16x8 vf1 = *(const bf16x8*)&Vs[vrow * 64 + ((32 + quad * 8) ^ g8)];
      acc[ob] = __builtin_amdgcn_mfma_f32_16x16x32_bf16(ap0, vf0, acc[ob], 0, 0, 0);
      acc[ob] = __builtin_amdgcn_mfma_f32_16x16x32_bf16(ap1, vf1, acc[ob], 0, 0, 0);
    }
  }
#pragma unroll
  for (int r = 0; r < 4; r++) {
    float inv = 1.0f / l_run[r];
    size_t rowoff =
        (size_t)(qrowbase + wave * 16 + quad * 4 + r) * D + h * 64;
#pragma unroll
    for (int ob = 0; ob < 4; ob++)
      out[rowoff + ob * 16 + l16] = f2bf(acc[ob][r] * inv);
  }
}

extern "C" void kernel_launch(void* const* d_in, const int* in_sizes, int n_in,
                              void* d_out, int out_size, void* d_ws,
                              size_t ws_size, hipStream_t stream) {
  const float* x    = (const float*)d_in[0];
  const int*   mask = (const int*)d_in[1];
  const float* wq = (const float*)d_in[2];   const float* bq = (const float*)d_in[3];
  const float* wk = (const float*)d_in[4];   const float* bk = (const float*)d_in[5];
  const float* wv = (const float*)d_in[6];   const float* bv = (const float*)d_in[7];
  const float* wo = (const float*)d_in[8];   const float* bo = (const float*)d_in[9];
  const float* w1 = (const float*)d_in[10];  const float* b1 = (const float*)d_in[11];
  const float* w2 = (const float*)d_in[12];  const float* b2 = (const float*)d_in[13];
  const float* ln1w = (const float*)d_in[14]; const float* ln1b = (const float*)d_in[15];
  const float* ln2w = (const float*)d_in[16]; const float* ln2b = (const float*)d_in[17];
  float* outp = (float*)d_out;

  // Workspace (MB): [0,6) wqkvT  [6,8) woT  [8,16) w1T  [16,24) w2T
  // [24,40) xn1 -> attn -> xn2 (sequential lifetimes)
  // [40,88) qkv  (dead after attention)  [40,104) hb alias (ffn1 out)
  // [88,88.012) bqkv (dead before hb written)   [104,136) y1 fp32
  char* ws = (char*)d_ws;
  const size_t MB = 1024 * 1024;
  u16* wqkvT = (u16*)(ws + 0 * MB);
  u16* woT   = (u16*)(ws + 6 * MB);
  u16* w1T   = (u16*)(ws + 8 * MB);
  u16* w2T   = (u16*)(ws + 16 * MB);
  u16* xn    = (u16*)(ws + 24 * MB);   // ln1 out; later attn out; later ln2 out
  u16* qkvb  = (u16*)(ws + 40 * MB);
  u16* hb    = (u16*)(ws + 40 * MB);   // alias (qkv dead by ffn1)
  float* bqkv = (float*)(ws + 88 * MB);
  float* y1  = (float*)(ws + 104 * MB);

  const float qscale = 0.125f;  // 1/sqrt(DK)

  k_transpose_bf16<<<dim3(32, 32), 256, 0, stream>>>(wq, wqkvT, 1024, 1024, qscale);
  k_transpose_bf16<<<dim3(32, 32), 256, 0, stream>>>(wk, wqkvT + 1024 * 1024, 1024, 1024, 1.0f);
  k_transpose_bf16<<<dim3(32, 32), 256, 0, stream>>>(wv, wqkvT + 2048 * 1024, 1024, 1024, 1.0f);
  k_transpose_bf16<<<dim3(32, 32), 256, 0, stream>>>(wo, woT, 1024, 1024, 1.0f);
  k_transpose_bf16<<<dim3(128, 32), 256, 0, stream>>>(w1, w1T, 1024, 4096, 1.0f);
  k_transpose_bf16<<<dim3(32, 128), 256, 0, stream>>>(w2, w2T, 4096, 1024, 1.0f);
  k_pack_bias<<<12, 256, 0, stream>>>(bq, bk, bv, bqkv, qscale);

  k_layernorm_bf16<<<8192, 256, 0, stream>>>(x, ln1w, ln1b, xn);

  // fused QKV: [8192,1024] @ [1024,3072] -> [8192,3072]
  k_gemm<false, false, true><<<dim3(24, 64), 256, 0, stream>>>(
      xn, wqkvT, bqkv, nullptr, qkvb, 8192, 3072, 1024);

  k_attention<<<1024, 512, 0, stream>>>(qkvb, mask, xn);  // attn out -> xn region

  dim3 g1(8, 64);
  k_gemm<false, true, false><<<g1, 256, 0, stream>>>(xn, woT, bo, x, y1, 8192, 1024, 1024);

  k_layernorm_bf16<<<8192, 256, 0, stream>>>(y1, ln2w, ln2b, xn);

  k_gemm<true, false, true><<<dim3(32, 64), 256, 0, stream>>>(
      xn, w1T, b1, nullptr, hb, 8192, 4096, 1024);

  k_gemm<false, true, false><<<g1, 256, 0, stream>>>(hb, w2T, b2, y1, outp, 8192, 1024, 4096);
}